// Round 3
// baseline (466.591 us; speedup 1.0000x reference)
//
#include <hip/hip_runtime.h>

// segments: (8,1,512,512) f32 vals 0..63; ::2 downsample -> (8,256,256)
// out: (8, 225, 256, 256) f32 = 471.9 MB. Write-BW floor ~75 us @6.3 TB/s.
//
// R3: plane-contiguous writes. prep_kernel stages zero-padded downsampled
// images (272x272 per batch) into d_ws; adj_kernel assigns one block per
// (quarter-plane, batch) so each block writes 64 KB sequentially (fill-like
// DRAM row locality). Pad zeros == jnp.pad zeros -> no bounds logic in the
// hot loop.

#define RAD 7
#define KS 15
#define HW 256
#define IN_W 512
#define P_PITCH 272                 // padded cols (8 left, 8 right)
#define P_OFF 8
#define IMG_P (P_PITCH * P_PITCH)   // 73984 floats per padded image
#define PLANE (HW * HW)

typedef float vf4  __attribute__((ext_vector_type(4)));
typedef float vf4u __attribute__((ext_vector_type(4), aligned(4)));

__global__ __launch_bounds__(256) void prep_kernel(const float* __restrict__ in,
                                                   float* __restrict__ staged) {
    const int r = blockIdx.x;       // padded row 0..271
    const int b = blockIdx.y;
    const float* inb = in + (size_t)b * (IN_W * IN_W);
    float* row = staged + (size_t)b * IMG_P + (size_t)r * P_PITCH;
    const int gy = r - P_OFF;
    for (int c = threadIdx.x; c < P_PITCH; c += 256) {
        const int gx = c - P_OFF;
        float v = 0.0f;
        if ((unsigned)gy < HW && (unsigned)gx < HW)
            v = inb[(size_t)(2 * gy) * IN_W + 2 * gx];
        row[c] = v;
    }
}

__global__ __launch_bounds__(256) void adj_kernel(const float* __restrict__ staged,
                                                  float* __restrict__ out) {
    const int kq = blockIdx.x;      // 0..899 : (k, quarter)
    const int b  = blockIdx.y;
    const int k  = kq >> 2;         // 0..224
    const int q  = kq & 3;          // quarter: rows 64q .. 64q+63
    const int dy = k / KS - RAD;
    const int dx = k % KS - RAD;

    const int t    = threadIdx.x;
    const int rsub = t >> 6;        // wave id -> row within 4-row group
    const int col  = (t & 63) * 4;  // lane -> 4 consecutive cols

    const float* img = staged + (size_t)b * IMG_P;
    const float* cen = img + (size_t)(P_OFF)      * P_PITCH + (P_OFF + col);
    const float* nbr = img + (size_t)(P_OFF + dy) * P_PITCH + (P_OFF + col + dx);

    float* op = out + ((size_t)b * (KS * KS) + k) * PLANE;

    const int row0 = q * 64;
    #pragma unroll 4
    for (int i = 0; i < 16; ++i) {
        const int row = row0 + i * 4 + rsub;
        vf4  c = *(const vf4*) (cen + (size_t)row * P_PITCH);
        vf4u n = *(const vf4u*)(nbr + (size_t)row * P_PITCH);
        vf4 v;
        v.x = (c.x == n.x) ? 1.0f : 0.0f;
        v.y = (c.y == n.y) ? 1.0f : 0.0f;
        v.z = (c.z == n.z) ? 1.0f : 0.0f;
        v.w = (c.w == n.w) ? 1.0f : 0.0f;
        __builtin_nontemporal_store(v, (vf4*)(op + (size_t)row * HW + col));
    }
}

extern "C" void kernel_launch(void* const* d_in, const int* in_sizes, int n_in,
                              void* d_out, int out_size, void* d_ws, size_t ws_size,
                              hipStream_t stream) {
    const float* segments = (const float*)d_in[0];
    float* out    = (float*)d_out;
    float* staged = (float*)d_ws;   // 8 * 73984 floats = 2.37 MB

    dim3 pgrid(P_PITCH, 8);
    prep_kernel<<<pgrid, dim3(256), 0, stream>>>(segments, staged);

    dim3 agrid(KS * KS * 4, 8);     // (plane-quarter, batch)
    adj_kernel<<<agrid, dim3(256), 0, stream>>>(staged, out);
}